// Round 2
// baseline (129.884 us; speedup 1.0000x reference)
//
#include <hip/hip_runtime.h>
#include <hip/hip_bf16.h>

// ---------------- types ----------------
typedef __bf16 bf16x8 __attribute__((ext_vector_type(8)));
typedef float  f32x4  __attribute__((ext_vector_type(4)));
typedef float  f32x4u __attribute__((ext_vector_type(4), aligned(4)));  // 4B-aligned vector load

// ---------------- problem constants ----------------
#define BATCH 128
#define NSOL  1027
#define IND   257           // input dim
#define EMB   256           // output dim
// output segment offsets (floats)
#define OUT_SRC  0ULL
#define OUT_CAND 32768ULL
#define OUT_DST  33587200ULL
#define OUT_DEP  33619968ULL

// workspace layout (bytes)
#define WFRAG_OFF 0          // cand W_eff, bf16, MFMA-A-fragment order: [kk(9)][ntg(16)][lane(64)][j(8)]
#define BEFF_OFF  147456     // b_eff fp32 [4][256]  (seg order: src,cand,dst,dep)
#define WT_OFF    151552     // W_eff fp32 [4][257][256] ([seg][k][e], e fastest)

// ---------------- prep: build effective weights ----------------
__global__ __launch_bounds__(256) void swne_prep(
    const float* __restrict__ Wsrc, const float* __restrict__ bsrc,
    const float* __restrict__ Wdst, const float* __restrict__ bdst,
    const float* __restrict__ Wdep, const float* __restrict__ bdep,
    const float* __restrict__ Wcand, const float* __restrict__ bcand,
    const float* __restrict__ Wreg, const float* __restrict__ breg,
    const float* __restrict__ Wrand, const float* __restrict__ iw,
    char* __restrict__ ws)
{
    const float a  = 1.0f / (1.0f + expf(-iw[0]));   // sigmoid(integration_weight)
    const float ca = 1.0f - a;
    const float sa = 0.1f * a;

    const float* Ws[4] = {Wsrc, Wcand, Wdst, Wdep};
    const float* Bs[4] = {bsrc, bcand, bdst, bdep};

    const int gid = blockIdx.x * 256 + threadIdx.x;
    const int gsz = gridDim.x * 256;

    // b_eff [4][256]
    float* beff = (float*)(ws + BEFF_OFF);
    for (int i = gid; i < 4 * EMB; i += gsz) {
        int seg = i >> 8, e = i & 255;
        beff[i] = ca * Bs[seg][e] + a * breg[e];
    }

    // W_eff transposed fp32 [4][257][256]
    float* wt = (float*)(ws + WT_OFF);
    for (int i = gid; i < 4 * IND * EMB; i += gsz) {
        int seg = i / (IND * EMB);
        int rem = i - seg * (IND * EMB);
        int k = rem >> 8, e = rem & 255;
        int si = e * IND + k;
        wt[i] = ca * Ws[seg][si] + a * Wreg[si] + sa * Wrand[si];
    }

    // cand W_eff bf16 in MFMA A-fragment order, K padded 257->288 with zeros
    __bf16* wfr = (__bf16*)(ws + WFRAG_OFF);
    for (int i = gid; i < 9 * 16 * 64 * 8; i += gsz) {
        int kk   = i >> 13;          // /8192
        int rem  = i & 8191;
        int ntg  = rem >> 9;         // /512
        int rem2 = rem & 511;
        int l    = rem2 >> 3;
        int j    = rem2 & 7;
        int e = ntg * 16 + (l & 15);
        int k = kk * 32 + (l >> 4) * 8 + j;
        float v = 0.0f;
        if (k < IND) {
            int si = e * IND + k;
            v = ca * Wcand[si] + a * Wreg[si] + sa * Wrand[si];
        }
        wfr[i] = (__bf16)v;
    }
}

// ---------------- main: 384 edge blocks + 4096 cand MFMA blocks ----------------
__global__ __launch_bounds__(256, 4) void swne_main(const float* __restrict__ sol,
                                                    const char* __restrict__ ws,
                                                    float* __restrict__ out)
{
    __shared__ float xrow[260];       // edge-path row stage only (1 KiB)
    const int tid = threadIdx.x;
    const int bid = blockIdx.x;
    const float* beff = (const float*)(ws + BEFF_OFF);

    if (bid < 384) {
        // ---- edge rows: src / dst / dep, one row per block, fp32 ----
        int s = bid >> 7;            // 0:src 1:dst 2:dep
        int b = bid & 127;
        int nrow  = (s == 0) ? 0 : (s == 1 ? 1025 : 1026);
        int segw  = (s == 0) ? 0 : (s == 1 ? 2 : 3);
        size_t outb = (s == 0) ? OUT_SRC : (s == 1 ? OUT_DST : OUT_DEP);
        const float* x = sol + (size_t)(b * NSOL + nrow) * IND;
        for (int i = tid; i < IND; i += 256) xrow[i] = x[i];
        __syncthreads();
        const float* wtp = (const float*)(ws + WT_OFF) + (size_t)segw * (IND * EMB) + tid;
        float s0 = 0.f, s1 = 0.f, s2 = 0.f, s3 = 0.f;
        #pragma unroll 4
        for (int k = 0; k < 256; k += 4) {
            s0 = fmaf(xrow[k + 0], wtp[(size_t)(k + 0) * 256], s0);
            s1 = fmaf(xrow[k + 1], wtp[(size_t)(k + 1) * 256], s1);
            s2 = fmaf(xrow[k + 2], wtp[(size_t)(k + 2) * 256], s2);
            s3 = fmaf(xrow[k + 3], wtp[(size_t)(k + 3) * 256], s3);
        }
        float sum = beff[segw * 256 + tid] + ((s0 + s1) + (s2 + s3))
                  + xrow[256] * wtp[(size_t)256 * 256];
        out[outb + (size_t)b * 256 + tid] = sum;
        return;
    }

    // ---- candidate rows: 32-row x 256-col tile per block, no LDS, no barrier ----
    const int cbid = bid - 384;
    const int bb = cbid >> 5;        // batch
    const int t  = cbid & 31;        // 32-row tile within the 1024 cand rows

    const int lane = tid & 63, wave = tid >> 6;
    const int rl = lane & 15, grp = lane >> 4;

    // per-lane A source rows (X): row = t*32 + rt*16 + rl of the cand segment
    const float* arow0 = sol + (size_t)(bb * NSOL + 1 + t * 32 + rl) * IND;
    const float* arow1 = arow0 + (size_t)16 * IND;

    f32x4 acc[2][4];
    #pragma unroll
    for (int rt = 0; rt < 2; ++rt)
        #pragma unroll
        for (int nt = 0; nt < 4; ++nt) {
            f32x4 z = {0.f, 0.f, 0.f, 0.f};
            acc[rt][nt] = z;
        }

    const bf16x8* wf8 = (const bf16x8*)(ws + WFRAG_OFF);
    const int ntb = wave * 4;        // this wave owns cols [wave*64, wave*64+64)

    #pragma unroll
    for (int kk = 0; kk < 9; ++kk) {
        const int k0 = kk * 32 + grp * 8;
        // A fragments (X rows) straight from global, f32 -> bf16 in-reg.
        // 4B-aligned vector loads; over-read past k=256 hits finite in-bounds data
        // and is multiplied by zero-padded W columns.
        bf16x8 af[2];
        #pragma unroll
        for (int rt = 0; rt < 2; ++rt) {
            const float* ap = (rt == 0 ? arow0 : arow1) + k0;
            f32x4 lo = *(const f32x4u*)(ap);
            f32x4 hi = *(const f32x4u*)(ap + 4);
            bf16x8 v;
            #pragma unroll
            for (int j = 0; j < 4; ++j) { v[j] = (__bf16)lo[j]; v[j + 4] = (__bf16)hi[j]; }
            af[rt] = v;
        }
        #pragma unroll
        for (int nt = 0; nt < 4; ++nt) {
            bf16x8 bv = wf8[(size_t)(kk * 16 + ntb + nt) * 64 + lane];
            #pragma unroll
            for (int rt = 0; rt < 2; ++rt)
                // A = W_eff fragment, B = X fragment  ->  D[e][m] (transposed):
                // lane: col m = rl, rows e = wave*64 + nt*16 + grp*4 + {0..3}
                acc[rt][nt] = __builtin_amdgcn_mfma_f32_16x16x32_bf16(bv, af[rt], acc[rt][nt], 0, 0, 0);
        }
    }

    // bias + vectorized store: each lane stores 4 consecutive e-columns per acc
    const float* bc = beff + 256;    // cand segment bias
    #pragma unroll
    for (int rt = 0; rt < 2; ++rt) {
        const size_t mrow = (size_t)(bb * 1024 + t * 32 + rt * 16 + rl);
        float* op = out + OUT_CAND + mrow * 256 + wave * 64 + grp * 4;
        #pragma unroll
        for (int nt = 0; nt < 4; ++nt) {
            f32x4 bv4 = *(const f32x4*)(bc + wave * 64 + nt * 16 + grp * 4);
            f32x4 r = acc[rt][nt] + bv4;
            *(f32x4*)(op + nt * 16) = r;
        }
    }
}

extern "C" void kernel_launch(void* const* d_in, const int* in_sizes, int n_in,
                              void* d_out, int out_size, void* d_ws, size_t ws_size,
                              hipStream_t stream) {
    const float* sol   = (const float*)d_in[0];
    const float* Wsrc  = (const float*)d_in[1];
    const float* bsrc  = (const float*)d_in[2];
    const float* Wdst  = (const float*)d_in[3];
    const float* bdst  = (const float*)d_in[4];
    const float* Wdep  = (const float*)d_in[5];
    const float* bdep  = (const float*)d_in[6];
    const float* Wcand = (const float*)d_in[7];
    const float* bcand = (const float*)d_in[8];
    const float* Wreg  = (const float*)d_in[9];
    const float* breg  = (const float*)d_in[10];
    const float* Wrand = (const float*)d_in[11];
    const float* iw    = (const float*)d_in[12];

    swne_prep<<<512, 256, 0, stream>>>(Wsrc, bsrc, Wdst, bdst, Wdep, bdep,
                                       Wcand, bcand, Wreg, breg, Wrand, iw,
                                       (char*)d_ws);
    swne_main<<<4480, 256, 0, stream>>>(sol, (const char*)d_ws, (float*)d_out);
}

// Round 3
// 78.993 us; speedup vs baseline: 1.6443x; 1.6443x over previous
//
#include <hip/hip_runtime.h>
#include <hip/hip_bf16.h>

// ---------------- types ----------------
typedef __bf16 bf16x8 __attribute__((ext_vector_type(8)));
typedef float  f32x4  __attribute__((ext_vector_type(4)));

// ---------------- problem constants ----------------
#define BATCH 128
#define NSOL  1027
#define IND   257           // input dim
#define EMB   256           // output dim
// output segment offsets (floats)
#define OUT_SRC  0ULL
#define OUT_CAND 32768ULL
#define OUT_DST  33587200ULL
#define OUT_DEP  33619968ULL

// workspace layout (bytes)
#define WFRAG_OFF 0          // cand W_eff bf16, MFMA-A-frag order [kk(8)][ntg(16)][lane(64)][j(8)] = 131072 B
#define BEFF_OFF  131072     // b_eff fp32 [4][256]
#define WT_OFF    135168     // W_eff fp32 [4][257][256] ([seg][k][e], e fastest)

// ---------------- prep: build effective weights ----------------
__global__ __launch_bounds__(256) void swne_prep(
    const float* __restrict__ Wsrc, const float* __restrict__ bsrc,
    const float* __restrict__ Wdst, const float* __restrict__ bdst,
    const float* __restrict__ Wdep, const float* __restrict__ bdep,
    const float* __restrict__ Wcand, const float* __restrict__ bcand,
    const float* __restrict__ Wreg, const float* __restrict__ breg,
    const float* __restrict__ Wrand, const float* __restrict__ iw,
    char* __restrict__ ws)
{
    const float a  = 1.0f / (1.0f + expf(-iw[0]));   // sigmoid(integration_weight)
    const float ca = 1.0f - a;
    const float sa = 0.1f * a;

    const float* Ws[4] = {Wsrc, Wcand, Wdst, Wdep};
    const float* Bs[4] = {bsrc, bcand, bdst, bdep};

    const int gid = blockIdx.x * 256 + threadIdx.x;
    const int gsz = gridDim.x * 256;

    float* beff = (float*)(ws + BEFF_OFF);
    for (int i = gid; i < 4 * EMB; i += gsz) {
        int seg = i >> 8, e = i & 255;
        beff[i] = ca * Bs[seg][e] + a * breg[e];
    }

    float* wt = (float*)(ws + WT_OFF);
    for (int i = gid; i < 4 * IND * EMB; i += gsz) {
        int seg = i / (IND * EMB);
        int rem = i - seg * (IND * EMB);
        int k = rem >> 8, e = rem & 255;
        int si = e * IND + k;
        wt[i] = ca * Ws[seg][si] + a * Wreg[si] + sa * Wrand[si];
    }

    // cand W_eff bf16 in MFMA A-fragment order, K = 0..255 (col 256 via epilogue)
    __bf16* wfr = (__bf16*)(ws + WFRAG_OFF);
    for (int i = gid; i < 8 * 16 * 64 * 8; i += gsz) {
        int kk   = i >> 13;
        int rem  = i & 8191;
        int ntg  = rem >> 9;
        int rem2 = rem & 511;
        int l    = rem2 >> 3;
        int j    = rem2 & 7;
        int e = ntg * 16 + (l & 15);
        int k = kk * 32 + (l >> 4) * 8 + j;
        int si = e * IND + k;
        wfr[i] = (__bf16)(ca * Wcand[si] + a * Wreg[si] + sa * Wrand[si]);
    }
}

// stage tile t (16 rows x 256 cols f32) into regs (coalesced b32 loads)
#define LOADT(t, sr) { \
  _Pragma("unroll") for (int rr = 0; rr < 4; ++rr) { \
    const float* rp_ = base + (size_t)((t) * 16 + wave * 4 + rr) * IND; \
    _Pragma("unroll") for (int q = 0; q < 4; ++q) sr[rr * 4 + q] = rp_[q * 64 + lane]; } }

// write staged regs into LDS buffer b with XOR swizzle (dw ^= (row&7)<<2)
#define WRITET(b, sr) { \
  _Pragma("unroll") for (int rr = 0; rr < 4; ++rr) { \
    const int r_ = wave * 4 + rr; \
    const int rs_ = (r_ & 7) << 2; \
    _Pragma("unroll") for (int q = 0; q < 4; ++q) \
      lds[((b) * 4096 + r_ * 256 + q * 64 + lane) ^ rs_] = sr[rr * 4 + q]; } }

// raw barrier: drain LDS ops only — staged global loads stay in flight (no vmcnt drain)
#define BARRIER() { asm volatile("s_waitcnt lgkmcnt(0)" ::: "memory"); \
  __builtin_amdgcn_s_barrier(); asm volatile("" ::: "memory"); }

// compute tiles t0,t1 from buffers b0,b1 (shared W-frag loads), epilogue + store
#define COMPUTE_STORE(t0, t1, b0, b1) { \
  f32x4 acc0[4], acc1[4]; \
  _Pragma("unroll") for (int nt = 0; nt < 4; ++nt) { \
    f32x4 z_ = {0.f, 0.f, 0.f, 0.f}; acc0[nt] = z_; acc1[nt] = z_; } \
  const int rs_ = (rl & 7) << 2; \
  _Pragma("unroll") for (int kk = 0; kk < 8; ++kk) { \
    const int dwb0_ = (b0) * 4096 + rl * 256 + kk * 32 + grp * 8; \
    const int dwb1_ = (b1) * 4096 + rl * 256 + kk * 32 + grp * 8; \
    f32x4 lo0 = *(const f32x4*)&lds[dwb0_ ^ rs_]; \
    f32x4 hi0 = *(const f32x4*)&lds[(dwb0_ + 4) ^ rs_]; \
    f32x4 lo1 = *(const f32x4*)&lds[dwb1_ ^ rs_]; \
    f32x4 hi1 = *(const f32x4*)&lds[(dwb1_ + 4) ^ rs_]; \
    bf16x8 x0, x1; \
    _Pragma("unroll") for (int j = 0; j < 4; ++j) { \
      x0[j] = (__bf16)lo0[j]; x0[j + 4] = (__bf16)hi0[j]; \
      x1[j] = (__bf16)lo1[j]; x1[j + 4] = (__bf16)hi1[j]; } \
    _Pragma("unroll") for (int nt = 0; nt < 4; ++nt) { \
      bf16x8 bv = wf8[(size_t)((kk * 16 + wave * 4 + nt) * 64 + lane)]; \
      acc0[nt] = __builtin_amdgcn_mfma_f32_16x16x32_bf16(bv, x0, acc0[nt], 0, 0, 0); \
      acc1[nt] = __builtin_amdgcn_mfma_f32_16x16x32_bf16(bv, x1, acc1[nt], 0, 0, 0); } } \
  const float xl0 = base[(size_t)((t0) * 16 + rl) * IND + 256]; \
  const float xl1 = base[(size_t)((t1) * 16 + rl) * IND + 256]; \
  float* op0 = out + OUT_CAND + ((size_t)bb * 1024 + row0 + (t0) * 16 + rl) * 256 + ecol; \
  float* op1 = out + OUT_CAND + ((size_t)bb * 1024 + row0 + (t1) * 16 + rl) * 256 + ecol; \
  _Pragma("unroll") for (int nt = 0; nt < 4; ++nt) { \
    f32x4 r0 = acc0[nt] + xl0 * w2564[nt] + bias4[nt]; \
    f32x4 r1 = acc1[nt] + xl1 * w2564[nt] + bias4[nt]; \
    *(f32x4*)(op0 + nt * 16) = r0; \
    *(f32x4*)(op1 + nt * 16) = r1; } }

// ---------------- main: 384 edge blocks + 2048 cand MFMA blocks ----------------
__global__ __launch_bounds__(256, 2) void swne_main(const float* __restrict__ sol,
                                                    const char* __restrict__ ws,
                                                    float* __restrict__ out)
{
    __shared__ float lds[16384];   // 64 KiB: 4 buffers x (16 rows x 256 f32), XOR-swizzled
    const int tid = threadIdx.x;
    const int bid = blockIdx.x;
    const float* beff = (const float*)(ws + BEFF_OFF);

    if (bid < 384) {
        // ---- edge rows: src / dst / dep, one row per block, fp32 ----
        int s = bid >> 7;            // 0:src 1:dst 2:dep
        int b = bid & 127;
        int nrow  = (s == 0) ? 0 : (s == 1 ? 1025 : 1026);
        int segw  = (s == 0) ? 0 : (s == 1 ? 2 : 3);
        size_t outb = (s == 0) ? OUT_SRC : (s == 1 ? OUT_DST : OUT_DEP);
        const float* x = sol + (size_t)(b * NSOL + nrow) * IND;
        for (int i = tid; i < IND; i += 256) lds[i] = x[i];
        __syncthreads();
        const float* wtp = (const float*)(ws + WT_OFF) + (size_t)segw * (IND * EMB) + tid;
        float s0 = 0.f, s1 = 0.f, s2 = 0.f, s3 = 0.f;
        #pragma unroll 4
        for (int k = 0; k < 256; k += 4) {
            s0 = fmaf(lds[k + 0], wtp[(size_t)(k + 0) * 256], s0);
            s1 = fmaf(lds[k + 1], wtp[(size_t)(k + 1) * 256], s1);
            s2 = fmaf(lds[k + 2], wtp[(size_t)(k + 2) * 256], s2);
            s3 = fmaf(lds[k + 3], wtp[(size_t)(k + 3) * 256], s3);
        }
        float sum = beff[segw * 256 + tid] + ((s0 + s1) + (s2 + s3))
                  + lds[256] * wtp[(size_t)256 * 256];
        out[outb + (size_t)b * 256 + tid] = sum;
        return;
    }

    // ---- candidate rows: 64 rows per block = 4 tiles of 16, pair-pipelined ----
    const int cb  = bid - 384;
    const int bb  = cb >> 4;          // batch
    const int row0 = (cb & 15) << 6;  // first cand row of this block
    const int lane = tid & 63, wave = tid >> 6;
    const int rl = lane & 15, grp = lane >> 4;
    const float* base = sol + ((size_t)bb * NSOL + 1 + row0) * IND;
    const bf16x8* wf8 = (const bf16x8*)(ws + WFRAG_OFF);
    const float* wt1 = (const float*)(ws + WT_OFF) + (size_t)(IND * EMB);  // seg 1 = cand
    const int ecol = wave * 64 + grp * 4;

    // per-wave constants: bias and k=256 weight column (4 consecutive e each)
    f32x4 bias4[4], w2564[4];
    #pragma unroll
    for (int nt = 0; nt < 4; ++nt) {
        bias4[nt]  = *(const f32x4*)(beff + 256 + ecol + nt * 16);
        w2564[nt]  = *(const f32x4*)(wt1 + 256 * 256 + ecol + nt * 16);
    }

    float srA[16], srB[16];

    // prologue: tiles 0,1 -> buffers 0,1
    LOADT(0, srA); LOADT(1, srB);
    WRITET(0, srA); WRITET(1, srB);
    BARRIER();

    // pair 0: prefetch tiles 2,3 early (T14); compute tiles 0,1; write-late; barrier
    LOADT(2, srA); LOADT(3, srB);
    COMPUTE_STORE(0, 1, 0, 1);
    WRITET(2, srA); WRITET(3, srB);
    BARRIER();

    // pair 1: compute tiles 2,3
    COMPUTE_STORE(2, 3, 2, 3);
}

extern "C" void kernel_launch(void* const* d_in, const int* in_sizes, int n_in,
                              void* d_out, int out_size, void* d_ws, size_t ws_size,
                              hipStream_t stream) {
    const float* sol   = (const float*)d_in[0];
    const float* Wsrc  = (const float*)d_in[1];
    const float* bsrc  = (const float*)d_in[2];
    const float* Wdst  = (const float*)d_in[3];
    const float* bdst  = (const float*)d_in[4];
    const float* Wdep  = (const float*)d_in[5];
    const float* bdep  = (const float*)d_in[6];
    const float* Wcand = (const float*)d_in[7];
    const float* bcand = (const float*)d_in[8];
    const float* Wreg  = (const float*)d_in[9];
    const float* breg  = (const float*)d_in[10];
    const float* Wrand = (const float*)d_in[11];
    const float* iw    = (const float*)d_in[12];

    swne_prep<<<512, 256, 0, stream>>>(Wsrc, bsrc, Wdst, bdst, Wdep, bdep,
                                       Wcand, bcand, Wreg, breg, Wrand, iw,
                                       (char*)d_ws);
    swne_main<<<2432, 256, 0, stream>>>(sol, (const char*)d_ws, (float*)d_out);
}

// Round 4
// 73.566 us; speedup vs baseline: 1.7656x; 1.0738x over previous
//
#include <hip/hip_runtime.h>
#include <hip/hip_bf16.h>

// ---------------- types ----------------
typedef __bf16 bf16x8 __attribute__((ext_vector_type(8)));
typedef __bf16 bf16x4 __attribute__((ext_vector_type(4)));
typedef float  f32x4  __attribute__((ext_vector_type(4)));
typedef float  f32x4u __attribute__((ext_vector_type(4), aligned(4)));

// ---------------- problem constants ----------------
#define BATCH 128
#define NSOL  1027
#define IND   257
#define EMB   256
#define OUT_SRC  0ULL
#define OUT_CAND 32768ULL
#define OUT_DST  33587200ULL
#define OUT_DEP  33619968ULL

// workspace layout (bytes)
#define WFRAG_OFF 0          // cand W_eff bf16, MFMA-A-frag order [kk(8)][ntg(16)][lane(64)][j(8)]
#define BEFF_OFF  131072     // b_eff fp32 [4][256]
#define WT_OFF    135168     // W_eff fp32 [4][257][256] ([seg][k][e], e fastest)

// LDS: 32 rows x 528B bf16 (stride 264 elems; 528 mod 256 == 16 -> conflict-free
// for both ds_write_b64 staging and ds_read_b128 fragment reads) + x256[32] f32
#define XSTRIDE_B 528
#define X256_OFF  16896      // 32*528
#define SMEM_BYTES 17024

// ---------------- prep: build effective weights ----------------
__global__ __launch_bounds__(256) void swne_prep(
    const float* __restrict__ Wsrc, const float* __restrict__ bsrc,
    const float* __restrict__ Wdst, const float* __restrict__ bdst,
    const float* __restrict__ Wdep, const float* __restrict__ bdep,
    const float* __restrict__ Wcand, const float* __restrict__ bcand,
    const float* __restrict__ Wreg, const float* __restrict__ breg,
    const float* __restrict__ Wrand, const float* __restrict__ iw,
    char* __restrict__ ws)
{
    const float a  = 1.0f / (1.0f + expf(-iw[0]));
    const float ca = 1.0f - a;
    const float sa = 0.1f * a;

    const float* Ws[4] = {Wsrc, Wcand, Wdst, Wdep};
    const float* Bs[4] = {bsrc, bcand, bdst, bdep};

    const int gid = blockIdx.x * 256 + threadIdx.x;
    const int gsz = gridDim.x * 256;

    float* beff = (float*)(ws + BEFF_OFF);
    for (int i = gid; i < 4 * EMB; i += gsz) {
        int seg = i >> 8, e = i & 255;
        beff[i] = ca * Bs[seg][e] + a * breg[e];
    }

    float* wt = (float*)(ws + WT_OFF);
    for (int i = gid; i < 4 * IND * EMB; i += gsz) {
        int seg = i / (IND * EMB);
        int rem = i - seg * (IND * EMB);
        int k = rem >> 8, e = rem & 255;
        int si = e * IND + k;
        wt[i] = ca * Ws[seg][si] + a * Wreg[si] + sa * Wrand[si];
    }

    // cand W_eff bf16, MFMA-A-frag order, k = 0..255 (col 256 via epilogue)
    __bf16* wfr = (__bf16*)(ws + WFRAG_OFF);
    for (int i = gid; i < 8 * 16 * 64 * 8; i += gsz) {
        int kk   = i >> 13;
        int rem  = i & 8191;
        int ntg  = rem >> 9;
        int rem2 = rem & 511;
        int l    = rem2 >> 3;
        int j    = rem2 & 7;
        int e = ntg * 16 + (l & 15);
        int k = kk * 32 + (l >> 4) * 8 + j;
        int si = e * IND + k;
        wfr[i] = (__bf16)(ca * Wcand[si] + a * Wreg[si] + sa * Wrand[si]);
    }
}

// ---------------- main: 384 edge blocks + 4096 cand MFMA blocks ----------------
__global__ __launch_bounds__(256, 4) void swne_main(const float* __restrict__ sol,
                                                    const char* __restrict__ ws,
                                                    float* __restrict__ out)
{
    __shared__ __align__(16) char smem[SMEM_BYTES];
    const int tid = threadIdx.x;
    const int bid = blockIdx.x;
    const float* beff = (const float*)(ws + BEFF_OFF);

    if (bid < 384) {
        // ---- edge rows: src / dst / dep, one row per block, fp32 ----
        float* xrow = (float*)smem;
        int s = bid >> 7;            // 0:src 1:dst 2:dep
        int b = bid & 127;
        int nrow  = (s == 0) ? 0 : (s == 1 ? 1025 : 1026);
        int segw  = (s == 0) ? 0 : (s == 1 ? 2 : 3);
        size_t outb = (s == 0) ? OUT_SRC : (s == 1 ? OUT_DST : OUT_DEP);
        const float* x = sol + (size_t)(b * NSOL + nrow) * IND;
        for (int i = tid; i < IND; i += 256) xrow[i] = x[i];
        __syncthreads();
        const float* wtp = (const float*)(ws + WT_OFF) + (size_t)segw * (IND * EMB) + tid;
        float s0 = 0.f, s1 = 0.f, s2 = 0.f, s3 = 0.f;
        #pragma unroll 4
        for (int k = 0; k < 256; k += 4) {
            s0 = fmaf(xrow[k + 0], wtp[(size_t)(k + 0) * 256], s0);
            s1 = fmaf(xrow[k + 1], wtp[(size_t)(k + 1) * 256], s1);
            s2 = fmaf(xrow[k + 2], wtp[(size_t)(k + 2) * 256], s2);
            s3 = fmaf(xrow[k + 3], wtp[(size_t)(k + 3) * 256], s3);
        }
        float sum = beff[segw * 256 + tid] + ((s0 + s1) + (s2 + s3))
                  + xrow[256] * wtp[(size_t)256 * 256];
        out[outb + (size_t)b * 256 + tid] = sum;
        return;
    }

    // ---- candidate rows: one 32-row x 256-col tile per block ----
    const int cb = bid - 384;
    const int bb = cb >> 5;          // batch
    const int t  = cb & 31;          // 32-row tile index
    const int lane = tid & 63, wave = tid >> 6;
    const int rl = lane & 15, grp = lane >> 4;

    const float* tbase = sol + ((size_t)bb * NSOL + 1 + t * 32) * IND;

    // stage: each wave converts 8 rows f32 -> bf16 into LDS (stride 528B)
    #pragma unroll
    for (int rr = 0; rr < 8; ++rr) {
        const int r = wave * 8 + rr;
        f32x4u v = *((const f32x4u*)(tbase + (size_t)r * IND) + lane);
        bf16x4 h;
        h[0] = (__bf16)v[0]; h[1] = (__bf16)v[1];
        h[2] = (__bf16)v[2]; h[3] = (__bf16)v[3];
        *(bf16x4*)(smem + r * XSTRIDE_B + lane * 8) = h;
    }
    if (tid < 32)
        *(float*)(smem + X256_OFF + tid * 4) = tbase[(size_t)tid * IND + 256];
    __syncthreads();

    f32x4 acc[2][4];
    #pragma unroll
    for (int rt = 0; rt < 2; ++rt)
        #pragma unroll
        for (int n = 0; n < 4; ++n) {
            f32x4 z = {0.f, 0.f, 0.f, 0.f};
            acc[rt][n] = z;
        }

    const bf16x8* wf8 = (const bf16x8*)(ws + WFRAG_OFF);

    #pragma unroll
    for (int kk = 0; kk < 8; ++kk) {
        bf16x8 a0 = *(const bf16x8*)(smem + rl * XSTRIDE_B + kk * 64 + grp * 16);
        bf16x8 a1 = *(const bf16x8*)(smem + (16 + rl) * XSTRIDE_B + kk * 64 + grp * 16);
        #pragma unroll
        for (int n = 0; n < 4; ++n) {
            bf16x8 wv = wf8[(size_t)((kk * 16 + wave * 4 + n) * 64 + lane)];
            acc[0][n] = __builtin_amdgcn_mfma_f32_16x16x32_bf16(wv, a0, acc[0][n], 0, 0, 0);
            acc[1][n] = __builtin_amdgcn_mfma_f32_16x16x32_bf16(wv, a1, acc[1][n], 0, 0, 0);
        }
    }

    // epilogue: bias + k=256 rank-1 term, f32x4 stores
    const float* bc   = beff + 256;                                   // cand bias
    const float* w256 = (const float*)(ws + WT_OFF) + (size_t)(IND * EMB) + 256 * 256;
    const int ecol = wave * 64 + grp * 4;

    #pragma unroll
    for (int rt = 0; rt < 2; ++rt) {
        const int row = rt * 16 + rl;
        const float xl = *(const float*)(smem + X256_OFF + row * 4);
        float* op = out + OUT_CAND + ((size_t)bb * 1024 + t * 32 + row) * 256 + ecol;
        #pragma unroll
        for (int n = 0; n < 4; ++n) {
            f32x4 b4 = *(const f32x4*)(bc + ecol + n * 16);
            f32x4 w4 = *(const f32x4*)(w256 + ecol + n * 16);
            f32x4 r = acc[rt][n] + xl * w4 + b4;
            *(f32x4*)(op + n * 16) = r;
        }
    }
}

extern "C" void kernel_launch(void* const* d_in, const int* in_sizes, int n_in,
                              void* d_out, int out_size, void* d_ws, size_t ws_size,
                              hipStream_t stream) {
    const float* sol   = (const float*)d_in[0];
    const float* Wsrc  = (const float*)d_in[1];
    const float* bsrc  = (const float*)d_in[2];
    const float* Wdst  = (const float*)d_in[3];
    const float* bdst  = (const float*)d_in[4];
    const float* Wdep  = (const float*)d_in[5];
    const float* bdep  = (const float*)d_in[6];
    const float* Wcand = (const float*)d_in[7];
    const float* bcand = (const float*)d_in[8];
    const float* Wreg  = (const float*)d_in[9];
    const float* breg  = (const float*)d_in[10];
    const float* Wrand = (const float*)d_in[11];
    const float* iw    = (const float*)d_in[12];

    swne_prep<<<512, 256, 0, stream>>>(Wsrc, bsrc, Wdst, bdst, Wdep, bdep,
                                       Wcand, bcand, Wreg, breg, Wrand, iw,
                                       (char*)d_ws);
    swne_main<<<4480, 256, 0, stream>>>(sol, (const char*)d_ws, (float*)d_out);
}